// Round 2
// baseline (114.050 us; speedup 1.0000x reference)
//
#include <hip/hip_runtime.h>

// Problem constants (fixed by the reference)
#define Bz 8
#define Cc 256
#define Hh 152
#define Ww 152
#define HWp (Hh*Ww)
#define Kk 1024
#define BK (Bz*Kk)
#define MARGIN_F 10.0f
#define BIGF 1e30f

// ---------------------------------------------------------------------------
// Kernel 0: init neg_min (float-bits of 1e30) and the 2-float accumulator.
// Must run every launch: harness poisons d_ws once and never re-poisons.
// ---------------------------------------------------------------------------
__global__ __launch_bounds__(256) void init_kernel(unsigned* __restrict__ neg,
                                                   float* __restrict__ acc) {
    int idx = blockIdx.x * 256 + threadIdx.x;
    if (idx < BK) neg[idx] = __float_as_uint(BIGF);
    if (idx < 2) acc[idx] = 0.0f;
}

// ---------------------------------------------------------------------------
// Kernel 1: gather + L2-normalize.  One block per (b,k); thread = channel c.
// emb[b,k,c] = scale * x[b,c,ind[b,k]] / max(||row||,1e-12)
// sq[b,k]    = sum_c emb^2  (== scale^2 up to rounding; needed for d2)
// Gather loads are inherently uncoalesced (stride H*W between lanes).
// ---------------------------------------------------------------------------
__global__ __launch_bounds__(256) void gather_norm(const float* __restrict__ x,
        const int* __restrict__ ind, const float* __restrict__ scale_p,
        float* __restrict__ emb, float* __restrict__ sq) {
    int bk = blockIdx.x;          // 0..8191
    int b  = bk >> 10;
    int c  = threadIdx.x;         // 0..255
    int hw = ind[bk];
    float v = x[(size_t)(b * Cc + c) * HWp + hw];
    float s = v * v;
    #pragma unroll
    for (int off = 32; off > 0; off >>= 1) s += __shfl_down(s, off);
    __shared__ float wsum[4];
    int lane = threadIdx.x & 63, w = threadIdx.x >> 6;
    if (lane == 0) wsum[w] = s;
    __syncthreads();
    float tot   = wsum[0] + wsum[1] + wsum[2] + wsum[3];
    float denom = fmaxf(sqrtf(tot), 1e-12f);
    float scl   = scale_p[0] / denom;
    emb[(size_t)bk * Cc + c] = v * scl;
    if (c == 0) sq[bk] = scl * scl * tot;
}

// ---------------------------------------------------------------------------
// Kernel 2: per-batch Gram tile (64x64, 4x4 register blocking) + fused
// masked-min.  Grid = (K/64, K/64, B) = 2048 blocks.
// LDS layout is XOR-swizzled per 16B group: elem (cc,row) lives at
//   cc*64 + ((row>>2 ^ (cc>>2)&15)<<2) + (row&3)
// -> transposed scalar stores are 2-way (free), fragment reads stay b128.
// d2 is clamped to >=0 BEFORE the min so duplicate-index pairs (the entire
// loss signal) survive the uint-bit atomicMin.
// ---------------------------------------------------------------------------
#define BT 64
__global__ __launch_bounds__(256) void gram_min(const float* __restrict__ emb,
        const float* __restrict__ sq, const int* __restrict__ mask,
        unsigned* __restrict__ neg) {
    __shared__ float As[64 * 64];
    __shared__ float Bs[64 * 64];
    int b  = blockIdx.z;
    int i0 = blockIdx.y * BT;
    int j0 = blockIdx.x * BT;
    int tid = threadIdx.x;
    int tx = tid & 15;            // j group
    int ty = tid >> 4;            // i group
    const float* eb = emb + (size_t)b * Kk * Cc;
    float acc[4][4] = {};

    for (int c0 = 0; c0 < Cc; c0 += 64) {
        #pragma unroll
        for (int l = 0; l < 4; ++l) {
            int idx = l * 256 + tid;
            int row = idx >> 4;       // 0..63
            int c4  = idx & 15;       // float4 index within the 64-c chunk
            float4 va = *(const float4*)(eb + (size_t)(i0 + row) * Cc + c0 + c4 * 4);
            float4 vb = *(const float4*)(eb + (size_t)(j0 + row) * Cc + c0 + c4 * 4);
            int rhi = row >> 2, rlo = row & 3;
            float av[4] = {va.x, va.y, va.z, va.w};
            float bv[4] = {vb.x, vb.y, vb.z, vb.w};
            #pragma unroll
            for (int u = 0; u < 4; ++u) {
                int cc = c4 * 4 + u;
                int fc = (cc >> 2) & 15;
                int sw = cc * 64 + ((rhi ^ fc) << 2) + rlo;
                As[sw] = av[u];
                Bs[sw] = bv[u];
            }
        }
        __syncthreads();
        #pragma unroll 8
        for (int cc = 0; cc < 64; ++cc) {
            int fc = (cc >> 2) & 15;
            float4 a4 = *(const float4*)(&As[cc * 64 + ((ty ^ fc) << 2)]);
            float4 b4 = *(const float4*)(&Bs[cc * 64 + ((tx ^ fc) << 2)]);
            float aa[4] = {a4.x, a4.y, a4.z, a4.w};
            float bb[4] = {b4.x, b4.y, b4.z, b4.w};
            #pragma unroll
            for (int ii = 0; ii < 4; ++ii)
                #pragma unroll
                for (int jj = 0; jj < 4; ++jj)
                    acc[ii][jj] += aa[ii] * bb[jj];
        }
        __syncthreads();
    }

    const float* sqb = sq + b * Kk;
    const int*   mb  = mask + b * Kk;
    float sj[4]; int jg[4]; bool jv[4];
    #pragma unroll
    for (int jj = 0; jj < 4; ++jj) {
        jg[jj] = j0 + tx * 4 + jj;
        sj[jj] = sqb[jg[jj]];
        jv[jj] = (mb[jg[jj]] != 0);
    }
    float m4[4];
    #pragma unroll
    for (int ii = 0; ii < 4; ++ii) {
        int ig = i0 + ty * 4 + ii;
        float si = sqb[ig];
        float mn = BIGF;
        #pragma unroll
        for (int jj = 0; jj < 4; ++jj) {
            float d2 = fmaxf(si + sj[jj] - 2.0f * acc[ii][jj], 0.0f);
            bool ok = jv[jj] && (jg[jj] != ig);
            mn = ok ? fminf(mn, d2) : mn;
        }
        m4[ii] = mn;
    }
    // min across the 16 lanes sharing the same ty (same 4 i-rows)
    #pragma unroll
    for (int off = 1; off < 16; off <<= 1) {
        #pragma unroll
        for (int ii = 0; ii < 4; ++ii)
            m4[ii] = fminf(m4[ii], __shfl_xor(m4[ii], off));
    }
    if (tx == 0) {
        #pragma unroll
        for (int ii = 0; ii < 4; ++ii)
            atomicMin(&neg[b * Kk + i0 + ty * 4 + ii], __float_as_uint(m4[ii]));
    }
}

// ---------------------------------------------------------------------------
// Kernel 3: hinge = max(margin - sqrt(min_d2), 0) over valid anchors; sum.
// ---------------------------------------------------------------------------
__global__ __launch_bounds__(256) void hinge_reduce(const unsigned* __restrict__ neg,
        const int* __restrict__ mask, float* __restrict__ acc) {
    int idx = blockIdx.x * 256 + threadIdx.x;   // grid = 32 -> idx < 8192
    float h = 0.f, v = 0.f;
    if (mask[idx] != 0) {
        float d = sqrtf(__uint_as_float(neg[idx]));
        h = fmaxf(MARGIN_F - d, 0.f);
        v = 1.f;
    }
    #pragma unroll
    for (int off = 32; off > 0; off >>= 1) {
        h += __shfl_down(h, off);
        v += __shfl_down(v, off);
    }
    __shared__ float sh[4], sv[4];
    int lane = threadIdx.x & 63, w = threadIdx.x >> 6;
    if (lane == 0) { sh[w] = h; sv[w] = v; }
    __syncthreads();
    if (threadIdx.x == 0) {
        atomicAdd(&acc[0], sh[0] + sh[1] + sh[2] + sh[3]);
        atomicAdd(&acc[1], sv[0] + sv[1] + sv[2] + sv[3]);
    }
}

__global__ void finalize(const float* __restrict__ acc, float* __restrict__ out) {
    out[0] = acc[0] / acc[1];
}

// ---------------------------------------------------------------------------
extern "C" void kernel_launch(void* const* d_in, const int* in_sizes, int n_in,
                              void* d_out, int out_size, void* d_ws, size_t ws_size,
                              hipStream_t stream) {
    const float* x     = (const float*)d_in[0];   // [B,C,H,W] fp32
    const int*   ind   = (const int*)d_in[1];     // [B,K] int32
    const int*   mask  = (const int*)d_in[2];     // [B,K] int32
    const float* scale = (const float*)d_in[3];   // scalar fp32
    float* out = (float*)d_out;

    // workspace layout: emb fp32 [B*K*C] | sq [B*K] | neg_min uint [B*K] | acc[2]
    float*    emb = (float*)d_ws;
    float*    sq  = emb + (size_t)Bz * Kk * Cc;
    unsigned* neg = (unsigned*)(sq + BK);
    float*    acc = (float*)(neg + BK);

    init_kernel<<<32, 256, 0, stream>>>(neg, acc);
    gather_norm<<<BK, 256, 0, stream>>>(x, ind, scale, emb, sq);
    dim3 g(Kk / BT, Kk / BT, Bz);
    gram_min<<<g, 256, 0, stream>>>(emb, sq, mask, neg);
    hinge_reduce<<<32, 256, 0, stream>>>(neg, mask, acc);
    finalize<<<1, 1, 0, stream>>>(acc, out);
}

// Round 3
// 74.963 us; speedup vs baseline: 1.5214x; 1.5214x over previous
//
#include <hip/hip_runtime.h>
#include <hip/hip_bf16.h>

// Problem constants (fixed by the reference)
#define Bz 8
#define Cc 256
#define HWp (152*152)
#define Kk 1024
#define BK (Bz*Kk)
#define MARGIN_F 10.0f
#define BIGF 1e30f

typedef __attribute__((ext_vector_type(8))) short bf16x8;  // 8 bf16 = 4 VGPRs
typedef __attribute__((ext_vector_type(4))) float f32x4;   // MFMA 16x16 accumulator

// ---------------------------------------------------------------------------
// Kernel 1: gather + L2-normalize + round to bf16.  ONE WAVE per (b,k):
// lane loads 4 channels (stride H*W apart -> inherently uncoalesced reads),
// wave shfl_xor reduce for the norm, bf16 round, second reduce for sq (sum of
// squares of the *rounded* values so d2 for duplicate rows stays ~0), then a
// coalesced 8B store.  Fused: neg_min init (harness poisons ws only once).
// ---------------------------------------------------------------------------
__global__ __launch_bounds__(256) void gather_norm(
    const float* __restrict__ x, const int* __restrict__ ind,
    const float* __restrict__ scale_p, __hip_bfloat16* __restrict__ embB,
    float* __restrict__ sq, unsigned* __restrict__ neg)
{
    int wid  = blockIdx.x * 4 + (threadIdx.x >> 6);   // bk in 0..8191
    int lane = threadIdx.x & 63;
    int b    = wid >> 10;
    int hw   = ind[wid];
    const float* xb = x + (size_t)b * Cc * HWp + hw;

    float v[4];
    #pragma unroll
    for (int q = 0; q < 4; ++q)
        v[q] = xb[(size_t)(lane * 4 + q) * HWp];

    float s = v[0]*v[0] + v[1]*v[1] + v[2]*v[2] + v[3]*v[3];
    #pragma unroll
    for (int off = 32; off; off >>= 1) s += __shfl_xor(s, off);

    float scl = scale_p[0] / fmaxf(sqrtf(s), 1e-12f);

    ushort e[4]; float s2 = 0.f;
    #pragma unroll
    for (int q = 0; q < 4; ++q) {
        __hip_bfloat16 h = __float2bfloat16(v[q] * scl);
        e[q] = __hip_bfloat16_raw(h).x;
        float vb = __bfloat162float(h);
        s2 += vb * vb;
    }
    #pragma unroll
    for (int off = 32; off; off >>= 1) s2 += __shfl_xor(s2, off);

    ushort* er = (ushort*)embB + (size_t)wid * Cc + lane * 4;
    *(ushort4*)er = make_ushort4(e[0], e[1], e[2], e[3]);

    if (lane == 0) { sq[wid] = s2; neg[wid] = __float_as_uint(BIGF); }
}

// ---------------------------------------------------------------------------
// Kernel 2: Gram via bf16 MFMA + fused masked-min.
// Grid (K/128, K/128, B) = 512 blocks x 256 thr (4 waves, 2x2 quadrants of
// 64x64).  No LDS: A/B fragments load straight from global (emb is 4 MB total,
// L2-resident).  mfma_f32_16x16x32_bf16 layouts:
//   A[i][k]: i = lane&15, k = 8*(lane>>4)+elem   (8 contiguous bf16 = 16B load)
//   B[k][j]: j = lane&15, k = 8*(lane>>4)+elem   (same pattern, rows of E)
//   D[i][j]: j = lane&15, i = 4*(lane>>4)+reg    (guide-verified, m89/m91)
// d2 clamped >= 0 BEFORE the min so duplicate-index pairs (the loss signal)
// survive the uint-bit atomicMin.
// ---------------------------------------------------------------------------
#define TILE 128
__global__ __launch_bounds__(256) void gram_mfma_min(
    const __hip_bfloat16* __restrict__ emb, const float* __restrict__ sq,
    const int* __restrict__ mask, unsigned* __restrict__ neg)
{
    int b  = blockIdx.z;
    int i0 = blockIdx.y * TILE;
    int j0 = blockIdx.x * TILE;
    int w  = threadIdx.x >> 6, l = threadIdx.x & 63;
    int wr = w >> 1, wc = w & 1;          // wave's 64x64 quadrant
    int lr = l & 15, lg = l >> 4;         // lane row / k-group

    const short* E = (const short*)emb + (size_t)b * Kk * Cc;
    int arow = i0 + wr * 64 + lr;
    int brow = j0 + wc * 64 + lr;

    f32x4 acc[4][4] = {};
    for (int k0 = 0; k0 < Cc; k0 += 32) {
        bf16x8 af[4], bfr[4];
        #pragma unroll
        for (int f = 0; f < 4; ++f) {
            af[f]  = *(const bf16x8*)(E + (size_t)(arow + f*16) * Cc + k0 + lg*8);
            bfr[f] = *(const bf16x8*)(E + (size_t)(brow + f*16) * Cc + k0 + lg*8);
        }
        #pragma unroll
        for (int fi = 0; fi < 4; ++fi)
            #pragma unroll
            for (int fj = 0; fj < 4; ++fj)
                acc[fi][fj] = __builtin_amdgcn_mfma_f32_16x16x32_bf16(
                                  af[fi], bfr[fj], acc[fi][fj], 0, 0, 0);
    }

    const float* sqb = sq + b * Kk;
    const int*   mb  = mask + b * Kk;
    float sjv[4]; int jgv[4]; bool jva[4];
    #pragma unroll
    for (int fj = 0; fj < 4; ++fj) {
        int jg = j0 + wc*64 + fj*16 + lr;
        jgv[fj] = jg; sjv[fj] = sqb[jg]; jva[fj] = (mb[jg] != 0);
    }
    #pragma unroll
    for (int fi = 0; fi < 4; ++fi) {
        #pragma unroll
        for (int r = 0; r < 4; ++r) {
            int ig = i0 + wr*64 + fi*16 + 4*lg + r;
            float si = sqb[ig];
            float m = BIGF;
            #pragma unroll
            for (int fj = 0; fj < 4; ++fj) {
                float d2 = fmaxf(si + sjv[fj] - 2.0f * acc[fi][fj][r], 0.0f);
                bool ok = jva[fj] && (jgv[fj] != ig);
                m = ok ? fminf(m, d2) : m;
            }
            #pragma unroll
            for (int off = 1; off < 16; off <<= 1)
                m = fminf(m, __shfl_xor(m, off));
            if (lr == 0)
                atomicMin(&neg[b * Kk + ig], __float_as_uint(m));
        }
    }
}

// ---------------------------------------------------------------------------
// Kernel 3: hinge + mean in ONE block (1024 thr): grid-stride over 8192,
// wave shfl reduce, LDS across 16 waves, write the scalar.
// ---------------------------------------------------------------------------
__global__ __launch_bounds__(1024) void hinge_final(
    const unsigned* __restrict__ neg, const int* __restrict__ mask,
    float* __restrict__ out)
{
    float h = 0.f, v = 0.f;
    for (int i = threadIdx.x; i < BK; i += 1024) {
        if (mask[i] != 0) {
            float d = sqrtf(__uint_as_float(neg[i]));
            h += fmaxf(MARGIN_F - d, 0.f);
            v += 1.f;
        }
    }
    #pragma unroll
    for (int off = 32; off; off >>= 1) {
        h += __shfl_xor(h, off);
        v += __shfl_xor(v, off);
    }
    __shared__ float sh[16], sv[16];
    int w = threadIdx.x >> 6;
    if ((threadIdx.x & 63) == 0) { sh[w] = h; sv[w] = v; }
    __syncthreads();
    if (threadIdx.x == 0) {
        float H = 0.f, V = 0.f;
        #pragma unroll
        for (int i = 0; i < 16; ++i) { H += sh[i]; V += sv[i]; }
        out[0] = H / V;
    }
}

// ---------------------------------------------------------------------------
extern "C" void kernel_launch(void* const* d_in, const int* in_sizes, int n_in,
                              void* d_out, int out_size, void* d_ws, size_t ws_size,
                              hipStream_t stream) {
    const float* x     = (const float*)d_in[0];   // [B,C,H,W] fp32
    const int*   ind   = (const int*)d_in[1];     // [B,K] int32
    const int*   mask  = (const int*)d_in[2];     // [B,K] int32
    const float* scale = (const float*)d_in[3];   // scalar fp32
    float* out = (float*)d_out;

    // ws layout: embB bf16 [B*K*C] (4 MB) | sq f32 [B*K] | neg u32 [B*K]
    __hip_bfloat16* embB = (__hip_bfloat16*)d_ws;
    float*    sq  = (float*)((char*)d_ws + (size_t)BK * Cc * sizeof(__hip_bfloat16));
    unsigned* neg = (unsigned*)(sq + BK);

    gather_norm<<<BK / 4, 256, 0, stream>>>(x, ind, scale, embB, sq, neg);
    dim3 g(Kk / TILE, Kk / TILE, Bz);
    gram_mfma_min<<<g, 256, 0, stream>>>(embB, sq, mask, neg);
    hinge_final<<<1, 1024, 0, stream>>>(neg, mask, out);
}